// Round 9
// baseline (3643.080 us; speedup 1.0000x reference)
//
#include <hip/hip_runtime.h>
#include <math.h>

namespace {
constexpr int kBL = 16 * 2048;
constexpr int kH = 256;
constexpr int kNOut = 12;
constexpr int kRows = 64;        // rows per block
constexpr int kThreads = 1024;   // 16 waves: 0-7 MFMA-role, 8-15 gate-role
constexpr int kS = 264;          // A row stride in shorts (16B-aligned, low-conflict)
constexpr int kGS = 40;          // gh row stride in floats (16B-aligned, ~4-way max)
constexpr int kWhh = 3 * kH * kH;
}

using short8 = __attribute__((ext_vector_type(8))) short;
using f32x4 = __attribute__((ext_vector_type(4))) float;

__device__ inline void bsplit(float v, short& h, short& l) {
  unsigned u = __float_as_uint(v);
  unsigned rh = u + 0x7FFFu + ((u >> 16) & 1u);   // RNE to bf16
  h = (short)(rh >> 16);
  float hf = __uint_as_float(rh & 0xFFFF0000u);
  float r = v - hf;                                // exact residual
  unsigned u2 = __float_as_uint(r);
  unsigned rl = u2 + 0x7FFFu + ((u2 >> 16) & 1u);
  l = (short)(rl >> 16);
}

// split w_hh [768][256] fp32 -> bf16 hi/lo planes in d_ws
__global__ void split_whh_kernel(const float* __restrict__ w,
                                 short* __restrict__ hi, short* __restrict__ lo) {
  const int i = (blockIdx.x * 256 + threadIdx.x) * 4;
  const float4 v = *reinterpret_cast<const float4*>(w + i);
  short4 h4, l4;
  bsplit(v.x, h4.x, l4.x);
  bsplit(v.y, h4.y, l4.y);
  bsplit(v.z, h4.z, l4.z);
  bsplit(v.w, h4.w, l4.w);
  *reinterpret_cast<short4*>(hi + i) = h4;
  *reinterpret_cast<short4*>(lo + i) = l4;
}

#define MFMA(A, B, C) __builtin_amdgcn_mfma_f32_16x16x32_bf16((A), (B), (C), 0, 0, 0)

__global__ __launch_bounds__(kThreads)
void rbq_ws_kernel(const float* __restrict__ emb,    // [BL][256]
                   const float* __restrict__ w_ih,   // [768]
                   const float* __restrict__ b_ih,   // [768]
                   const float* __restrict__ b_hh,   // [768]
                   const float* __restrict__ w_out,  // [256]
                   const float* __restrict__ b_out,  // [1]
                   const short* __restrict__ Bh,     // [768][256] bf16 hi
                   const short* __restrict__ Bl,     // [768][256] bf16 lo
                   float* __restrict__ out) {        // [2][BL][12]
  __shared__ short Ah[kRows][kS];            // h_in hi (single buffer)
  __shared__ short Al[kRows][kS];            // h_in lo
  __shared__ float ghb[2][3][kRows][kGS];    // gh chunk double-buffer [g][row][unit_loc]
  __shared__ float prm[kH][8];               // {wir,wiz,win, bir+bhr, biz+bhz, bin, bhn, wo}
  __shared__ float xq[kRows];                // quantized feedback

  const int tid = threadIdx.x;
  const int lane = tid & 63;
  const int wv = __builtin_amdgcn_readfirstlane(tid >> 6);  // 0..15
  const int row0 = blockIdx.x * kRows;
  const size_t q_off = (size_t)kBL * kNOut;
  const float bo = b_out[0];

  // MFMA-role coordinates (waves 0..7): wave owns 16 rows (rt) x 16 units (u16) x 3 gates
  const int grp = lane >> 4;
  const int c16 = lane & 15;
  const int rt = wv & 3;
  const int u16 = (wv >> 2) & 1;

  // gate-role coordinates (waves 8..15): thread owns 1 row, 4 units per chunk
  const int grow = ((wv - 8) << 3) | (lane >> 3);  // 0..63
  const int sub = lane & 7;                        // 0..7

  // ---- init ----
  f32x4 h4[8];     // gate-role: exact h_in for its 32 units (h4[c][i], c=chunk)
  float opart = 0.0f;

  if (tid < kH) {  // params -> LDS (done by MFMA-side threads)
    const int u = tid;
    prm[u][0] = w_ih[u];
    prm[u][1] = w_ih[kH + u];
    prm[u][2] = w_ih[2 * kH + u];
    prm[u][3] = b_ih[u] + b_hh[u];
    prm[u][4] = b_ih[kH + u] + b_hh[kH + u];
    prm[u][5] = b_ih[2 * kH + u];
    prm[u][6] = b_hh[2 * kH + u];
    prm[u][7] = w_out[u];
  }
  if (wv >= 8) {   // h0 = 0 -> h_in = e; write A(0); xq = 0
#pragma unroll
    for (int c = 0; c < 8; ++c) {
      const f32x4 ev = *reinterpret_cast<const f32x4*>(
          emb + (size_t)(row0 + grow) * kH + c * 32 + sub * 4);
      h4[c] = ev;
      short4 hi4, lo4;
      bsplit(ev[0], hi4.x, lo4.x);
      bsplit(ev[1], hi4.y, lo4.y);
      bsplit(ev[2], hi4.z, lo4.z);
      bsplit(ev[3], hi4.w, lo4.w);
      *reinterpret_cast<short4*>(&Ah[grow][c * 32 + sub * 4]) = hi4;
      *reinterpret_cast<short4*>(&Al[grow][c * 32 + sub * 4]) = lo4;
    }
    if (sub == 0) xq[grow] = 0.0f;
  }
  __syncthreads();

  // ---- MFMA-role chunk: gh for chunk p (units 32p..32p+32), all 64 rows ----
  auto mfma_chunk = [&](const int p) {
    const int pb = p & 1;
    f32x4 a0 = {0.f, 0.f, 0.f, 0.f}, a1 = a0, a2 = a0;
    const short* __restrict__ b0 =
        Bh + ((size_t)(p * 32 + u16 * 16 + c16)) * kH;        // gate r row
    const short* __restrict__ b0l =
        Bl + ((size_t)(p * 32 + u16 * 16 + c16)) * kH;
    __builtin_amdgcn_s_setprio(1);
#pragma unroll
    for (int kc = 0; kc < 8; ++kc) {
      const int ko = kc * 32 + grp * 8;
      const short8 ah = *reinterpret_cast<const short8*>(&Ah[rt * 16 + c16][ko]);
      const short8 al = *reinterpret_cast<const short8*>(&Al[rt * 16 + c16][ko]);
      const short8 bh0 = *reinterpret_cast<const short8*>(b0 + ko);
      const short8 bh1 = *reinterpret_cast<const short8*>(b0 + 256 * kH + ko);
      const short8 bh2 = *reinterpret_cast<const short8*>(b0 + 512 * kH + ko);
      const short8 bl0 = *reinterpret_cast<const short8*>(b0l + ko);
      const short8 bl1 = *reinterpret_cast<const short8*>(b0l + 256 * kH + ko);
      const short8 bl2 = *reinterpret_cast<const short8*>(b0l + 512 * kH + ko);
      // per-acc pass order hh, lh, hl (as r2/r4); g-interleaved for dep distance
      a0 = MFMA(ah, bh0, a0); a1 = MFMA(ah, bh1, a1); a2 = MFMA(ah, bh2, a2);
      a0 = MFMA(al, bh0, a0); a1 = MFMA(al, bh1, a1); a2 = MFMA(al, bh2, a2);
      a0 = MFMA(ah, bl0, a0); a1 = MFMA(ah, bl1, a1); a2 = MFMA(ah, bl2, a2);
    }
    __builtin_amdgcn_s_setprio(0);
    const int urow = u16 * 16 + c16;
#pragma unroll
    for (int r2 = 0; r2 < 4; ++r2) {
      const int mrow = rt * 16 + grp * 4 + r2;   // C-layout: row=(lane>>4)*4+reg
      ghb[pb][0][mrow][urow] = a0[r2];
      ghb[pb][1][mrow][urow] = a1[r2];
      ghb[pb][2][mrow][urow] = a2[r2];
    }
  };

  // ---- gate-role chunk: consume gh chunk c, update h (exact), o-partials ----
  float xrow = 0.0f;
  auto gate_chunk = [&](const int c) {
    const int cb = c & 1;
    if (c == 0) xrow = xq[grow];     // q(step-1), barrier-protected
    const f32x4 ev = *reinterpret_cast<const f32x4*>(
        emb + (size_t)(row0 + grow) * kH + c * 32 + sub * 4);
    const f32x4 g0 = *reinterpret_cast<const f32x4*>(&ghb[cb][0][grow][sub * 4]);
    const f32x4 g1 = *reinterpret_cast<const f32x4*>(&ghb[cb][1][grow][sub * 4]);
    const f32x4 g2 = *reinterpret_cast<const f32x4*>(&ghb[cb][2][grow][sub * 4]);
    f32x4 hc = h4[c];
#pragma unroll
    for (int i = 0; i < 4; ++i) {
      const int j = c * 32 + sub * 4 + i;
      const f32x4 pa = *reinterpret_cast<const f32x4*>(&prm[j][0]);
      const f32x4 pb4 = *reinterpret_cast<const f32x4*>(&prm[j][4]);
      const float gr = fmaf(xrow, pa[0], pa[3]) + g0[i];
      const float gz = fmaf(xrow, pa[1], pb4[0]) + g1[i];
      const float gni = fmaf(xrow, pa[2], pb4[1]);
      const float rg = 1.0f / (1.0f + __expf(-gr));
      const float zg = 1.0f / (1.0f + __expf(-gz));
      const float ta = gni + rg * (g2[i] + pb4[2]);
      const float at = fabsf(ta);
      const float et = __expf(-2.0f * at);
      const float th = copysignf((1.0f - et) / (1.0f + et), ta);
      const float hn = fmaf(zg, hc[i] - th, th);     // (1-z)*n + z*h_in
      opart = fmaf(hn, pb4[3], opart);               // o partial
      hc[i] = hn + ev[i];                            // next h_in (exact fp32)
    }
    h4[c] = hc;
  };

  // ---- gate-role finalize: o, q, xq, output; rewrite A from register h ----
  auto finalize = [&](const int step) {
    float o = opart;
    o += __shfl_xor(o, 1, 8);
    o += __shfl_xor(o, 2, 8);
    o += __shfl_xor(o, 4, 8);
    o += bo;
    const float q = o > 0.0f ? 1.0f : -1.0f;
    if (sub == 0) {
      const size_t gr = (size_t)(row0 + grow);
      out[gr * kNOut + step] = o;
      out[q_off + gr * kNOut + step] = q;
      xq[grow] = q;
    }
    opart = 0.0f;
    if (step < kNOut - 1) {
#pragma unroll
      for (int c = 0; c < 8; ++c) {
        short4 hi4, lo4;
        bsplit(h4[c][0], hi4.x, lo4.x);
        bsplit(h4[c][1], hi4.y, lo4.y);
        bsplit(h4[c][2], hi4.z, lo4.z);
        bsplit(h4[c][3], hi4.w, lo4.w);
        *reinterpret_cast<short4*>(&Ah[grow][c * 32 + sub * 4]) = hi4;
        *reinterpret_cast<short4*>(&Al[grow][c * 32 + sub * 4]) = lo4;
      }
    }
  };

  // ---- main loop: 9 pipelined phases per step, one barrier each ----
  for (int step = 0; step < kNOut; ++step) {
#pragma unroll
    for (int p = 0; p < 9; ++p) {
      if (wv < 8) {
        if (p < 8) mfma_chunk(p);
      } else {
        if (p >= 1) gate_chunk(p - 1);
        if (p == 8) finalize(step);
      }
      __syncthreads();
    }
  }
}

extern "C" void kernel_launch(void* const* d_in, const int* in_sizes, int n_in,
                              void* d_out, int out_size, void* d_ws, size_t ws_size,
                              hipStream_t stream) {
  (void)in_sizes; (void)n_in; (void)out_size; (void)ws_size;
  const float* emb = (const float*)d_in[0];
  const float* w_ih = (const float*)d_in[1];
  const float* w_hh = (const float*)d_in[2];
  const float* b_ih = (const float*)d_in[3];
  const float* b_hh = (const float*)d_in[4];
  const float* w_out = (const float*)d_in[5];
  const float* b_out = (const float*)d_in[6];

  short* Bh = (short*)d_ws;                  // [768][256] bf16 hi
  short* Bl = Bh + kWhh;                     // [768][256] bf16 lo (768 KiB total)

  split_whh_kernel<<<kWhh / (256 * 4), 256, 0, stream>>>(w_hh, Bh, Bl);
  rbq_ws_kernel<<<kBL / kRows, kThreads, 0, stream>>>(
      emb, w_ih, b_ih, b_hh, w_out, b_out, Bh, Bl, (float*)d_out);
}